// Round 3
// baseline (11651.389 us; speedup 1.0000x reference)
//
#include <hip/hip_runtime.h>
#include <hip/hip_bf16.h>

namespace {

constexpr int T_SEQ = 512;
constexpr int B_SZ  = 1024;
constexpr int H_DIM = 128;
constexpr int RPB   = 4;       // batch rows per block
constexpr int NTHR  = 1024;    // 16 waves, 1 block/CU, 128-VGPR cap
constexpr int KS    = 8;       // K split factor

__device__ __forceinline__ float fast_sigmoid(float x) {
  x = fminf(fmaxf(x, -30.f), 30.f);
  const float e = __expf(-x);
  return 1.f / (1.f + e);
}
__device__ __forceinline__ float fast_tanh(float x) {
  x = fminf(fmaxf(x, -15.f), 15.f);
  const float e = __expf(2.f * x);
  return 1.f - 2.f / (e + 1.f);
}

__device__ __forceinline__ float ld_in(const float* p) { return *p; }
__device__ __forceinline__ float ld_in(const __hip_bfloat16* p) { return __bfloat162float(*p); }
__device__ __forceinline__ void st_out(float* p, float v) { *p = v; }
__device__ __forceinline__ void st_out(__hip_bfloat16* p, float v) { *p = __float2bfloat16(v); }

// One GRU layer. Block owns RPB batch rows for the whole sequence.
// Thread (j = tid&127, k8 = tid>>7) owns gate rows {j, j+H, j+2H} x K-eighth
// k8 of BOTH w_ih and w_hh: 96 fp32 weights (l1) / 72 (l0) -> fits the
// 128-VGPR cap of __launch_bounds__(1024,4) in ARCH VGPRs (no AGPR moves).
// x/h broadcast-read from LDS (wave-uniform addresses, conflict-free).
template <int INDIM, typename InT, typename OutT, bool STORE_ALL>
__global__ __launch_bounds__(NTHR, 4)
void gru_layer_kernel(const InT*  __restrict__ in,     // (B, T, INDIM)
                      const float* __restrict__ w_ih,  // (3H, INDIM)
                      const float* __restrict__ w_hh,  // (3H, H)
                      const float* __restrict__ b_ih,  // (3H)
                      const float* __restrict__ b_hh,  // (3H)
                      OutT* __restrict__ out)          // STORE_ALL ? (B,T,H) : (B,H)
{
  constexpr int KQI = INDIM / KS;  // per-thread w_ih K-slice (l0: 8, l1: 16)
  constexpr int KQH = H_DIM / KS;  // per-thread w_hh K-slice (16)

  const int tid = threadIdx.x;
  const int j   = tid & (H_DIM - 1);
  const int k8  = tid >> 7;        // 0..7
  const int r0  = blockIdx.x * RPB;

  __shared__ __align__(16) float  h_s[RPB][H_DIM];
  __shared__ __align__(16) float  in_s[RPB][INDIM];
  __shared__ __align__(16) float4 part[RPB][KS][H_DIM]; // (r, k8, j) -> (ar, az, xn, hn)

  if (tid < RPB * H_DIM) h_s[tid >> 7][tid & (H_DIM - 1)] = 0.f;

  // ---- weights -> arch VGPRs (once) ----
  float wi[3][KQI];
  float wh[3][KQH];
  #pragma unroll
  for (int g = 0; g < 3; ++g) {
    const float4* si = reinterpret_cast<const float4*>(
        w_ih + (size_t)(g * H_DIM + j) * INDIM + k8 * KQI);
    #pragma unroll
    for (int k4 = 0; k4 < KQI / 4; ++k4) {
      const float4 v = si[k4];
      wi[g][4*k4+0] = v.x; wi[g][4*k4+1] = v.y; wi[g][4*k4+2] = v.z; wi[g][4*k4+3] = v.w;
    }
    const float4* sh = reinterpret_cast<const float4*>(
        w_hh + (size_t)(g * H_DIM + j) * H_DIM + k8 * KQH);
    #pragma unroll
    for (int k4 = 0; k4 < KQH / 4; ++k4) {
      const float4 v = sh[k4];
      wh[g][4*k4+0] = v.x; wh[g][4*k4+1] = v.y; wh[g][4*k4+2] = v.z; wh[g][4*k4+3] = v.w;
    }
  }
  // combine-phase constants (thread's combine task is (tid>>7, j), tid<512)
  const float bir  = b_ih[j],            bhr = b_hh[j];
  const float biz  = b_ih[H_DIM + j],    bhz = b_hh[H_DIM + j];
  const float bin_ = b_ih[2*H_DIM + j],  bhn = b_hh[2*H_DIM + j];

  // ---- stage t=0 input ----
  const int sr = tid / INDIM;      // INDIM is pow2
  const int sc = tid & (INDIM - 1);
  const bool do_stage = (tid < RPB * INDIM);
  float stg = 0.f;
  if (do_stage) stg = ld_in(in + (size_t)(r0 + sr) * T_SEQ * INDIM + sc);

  __syncthreads();   // h_s init visible

  #pragma unroll 1
  for (int t = 0; t < T_SEQ; ++t) {
    if (do_stage) in_s[sr][sc] = stg;
    __syncthreads();                       // [B1] in_s + h_s ready

    if (do_stage && (t + 1 < T_SEQ))
      stg = ld_in(in + (size_t)(r0 + sr) * T_SEQ * INDIM + (size_t)(t + 1) * INDIM + sc);

    // partial dot products for all RPB rows (wave-uniform LDS broadcasts)
    #pragma unroll
    for (int r = 0; r < RPB; ++r) {
      float a0 = 0.f, a1 = 0.f, a2 = 0.f, a3 = 0.f;  // r, z, xn, hn
      const float4* xq = reinterpret_cast<const float4*>(&in_s[r][k8 * KQI]);
      #pragma unroll
      for (int k4 = 0; k4 < KQI / 4; ++k4) {
        const float4 v = xq[k4];
        a0 += wi[0][4*k4+0]*v.x; a0 += wi[0][4*k4+1]*v.y; a0 += wi[0][4*k4+2]*v.z; a0 += wi[0][4*k4+3]*v.w;
        a1 += wi[1][4*k4+0]*v.x; a1 += wi[1][4*k4+1]*v.y; a1 += wi[1][4*k4+2]*v.z; a1 += wi[1][4*k4+3]*v.w;
        a2 += wi[2][4*k4+0]*v.x; a2 += wi[2][4*k4+1]*v.y; a2 += wi[2][4*k4+2]*v.z; a2 += wi[2][4*k4+3]*v.w;
      }
      const float4* hq = reinterpret_cast<const float4*>(&h_s[r][k8 * KQH]);
      #pragma unroll
      for (int k4 = 0; k4 < KQH / 4; ++k4) {
        const float4 v = hq[k4];
        a0 += wh[0][4*k4+0]*v.x; a0 += wh[0][4*k4+1]*v.y; a0 += wh[0][4*k4+2]*v.z; a0 += wh[0][4*k4+3]*v.w;
        a1 += wh[1][4*k4+0]*v.x; a1 += wh[1][4*k4+1]*v.y; a1 += wh[1][4*k4+2]*v.z; a1 += wh[1][4*k4+3]*v.w;
        a3 += wh[2][4*k4+0]*v.x; a3 += wh[2][4*k4+1]*v.y; a3 += wh[2][4*k4+2]*v.z; a3 += wh[2][4*k4+3]*v.w;
      }
      part[r][k8][j] = make_float4(a0, a1, a2, a3);
    }
    __syncthreads();                       // [B2] partials ready

    // gate combine: 512 tasks on threads 0..511 (8 waves)
    if (tid < RPB * H_DIM) {
      const int rr = tid >> 7;
      const int jj = j;
      float4 s = part[rr][0][jj];
      #pragma unroll
      for (int kk = 1; kk < KS; ++kk) {
        const float4 p = part[rr][kk][jj];
        s.x += p.x; s.y += p.y; s.z += p.z; s.w += p.w;
      }
      const float rg = fast_sigmoid(s.x + bir + bhr);
      const float zg = fast_sigmoid(s.y + biz + bhz);
      const float ng = fast_tanh(s.z + bin_ + rg * (s.w + bhn));
      const float hv = (1.f - zg) * ng + zg * h_s[rr][jj];
      h_s[rr][jj] = hv;
      if (STORE_ALL) {
        st_out(out + ((size_t)(r0 + rr) * T_SEQ + t) * H_DIM + jj, hv);
      } else if (t == T_SEQ - 1) {
        st_out(out + (size_t)(r0 + rr) * H_DIM + jj, hv);
      }
    }
    // next iteration's [B1] orders the h_s update vs. the partial phase.
  }
}

// FC head: out = fc2( BN( relu( fc1(h2_last) ) ) ); one row per block.
__global__ __launch_bounds__(64)
void head_kernel(const float* __restrict__ h2,     // (B, H)
                 const float* __restrict__ fc1_w,  // (64, 128)
                 const float* __restrict__ fc1_b,  // (64)
                 const float* __restrict__ fc2_w,  // (2, 64)
                 const float* __restrict__ fc2_b,  // (2)
                 const float* __restrict__ gamma,
                 const float* __restrict__ beta,
                 const float* __restrict__ mean,
                 const float* __restrict__ var,
                 float* __restrict__ out)          // (B, 2)
{
  const int row = blockIdx.x;
  const int j   = threadIdx.x;   // 0..63
  __shared__ __align__(16) float hrow[H_DIM];
  __shared__ __align__(16) float act[64];

  hrow[j]      = h2[(size_t)row * H_DIM + j];
  hrow[64 + j] = h2[(size_t)row * H_DIM + 64 + j];
  __syncthreads();

  float s = fc1_b[j];
  const float4* wr = reinterpret_cast<const float4*>(fc1_w + (size_t)j * H_DIM);
  #pragma unroll
  for (int k4 = 0; k4 < H_DIM / 4; ++k4) {
    const float4 w = wr[k4];
    const float4 h = reinterpret_cast<const float4*>(hrow)[k4];
    s += w.x * h.x + w.y * h.y + w.z * h.z + w.w * h.w;
  }
  s = fmaxf(s, 0.f);
  s = (s - mean[j]) * rsqrtf(var[j] + 1e-5f) * gamma[j] + beta[j];
  act[j] = s;
  __syncthreads();

  if (j < 2) {
    float o = fc2_b[j];
    #pragma unroll
    for (int k = 0; k < 64; ++k) o += fc2_w[(size_t)j * 64 + k] * act[k];
    out[(size_t)row * 2 + j] = o;
  }
}

} // namespace

extern "C" void kernel_launch(void* const* d_in, const int* in_sizes, int n_in,
                              void* d_out, int out_size, void* d_ws, size_t ws_size,
                              hipStream_t stream) {
  const float* x     = (const float*)d_in[0];
  const float* w_ih0 = (const float*)d_in[1];
  const float* w_hh0 = (const float*)d_in[2];
  const float* b_ih0 = (const float*)d_in[3];
  const float* b_hh0 = (const float*)d_in[4];
  const float* w_ih1 = (const float*)d_in[5];
  const float* w_hh1 = (const float*)d_in[6];
  const float* b_ih1 = (const float*)d_in[7];
  const float* b_hh1 = (const float*)d_in[8];
  const float* fc1_w = (const float*)d_in[9];
  const float* fc1_b = (const float*)d_in[10];
  const float* fc2_w = (const float*)d_in[11];
  const float* fc2_b = (const float*)d_in[12];
  const float* gamma = (const float*)d_in[13];
  const float* beta  = (const float*)d_in[14];
  const float* mean  = (const float*)d_in[15];
  const float* var   = (const float*)d_in[16];
  float* out = (float*)d_out;

  char* ws = (char*)d_ws;
  const size_t h2_bytes  = (size_t)B_SZ * H_DIM * sizeof(float);
  float* h2_last = (float*)ws;
  char*  h1_raw  = ws + h2_bytes;
  const size_t h1_elems = (size_t)B_SZ * T_SEQ * H_DIM;

  const dim3 gridG(B_SZ / RPB);
  const dim3 blockG(NTHR);

  if (ws_size >= h2_bytes + h1_elems * sizeof(float)) {
    float* h1 = (float*)h1_raw;
    gru_layer_kernel<64, float, float, true>
        <<<gridG, blockG, 0, stream>>>(x, w_ih0, w_hh0, b_ih0, b_hh0, h1);
    gru_layer_kernel<128, float, float, false>
        <<<gridG, blockG, 0, stream>>>(h1, w_ih1, w_hh1, b_ih1, b_hh1, h2_last);
  } else if (ws_size >= h2_bytes + h1_elems * sizeof(__hip_bfloat16)) {
    __hip_bfloat16* h1 = (__hip_bfloat16*)h1_raw;
    gru_layer_kernel<64, float, __hip_bfloat16, true>
        <<<gridG, blockG, 0, stream>>>(x, w_ih0, w_hh0, b_ih0, b_hh0, h1);
    gru_layer_kernel<128, __hip_bfloat16, float, false>
        <<<gridG, blockG, 0, stream>>>(h1, w_ih1, w_hh1, b_ih1, b_hh1, h2_last);
  } else {
    return;  // workspace too small for any valid plan — fail visibly
  }

  head_kernel<<<dim3(B_SZ), dim3(64), 0, stream>>>(
      h2_last, fc1_w, fc1_b, fc2_w, fc2_b, gamma, beta, mean, var, out);
}

// Round 4
// 1305.009 us; speedup vs baseline: 8.9282x; 8.9282x over previous
//
#include <hip/hip_runtime.h>
#include <hip/hip_bf16.h>

namespace {

typedef _Float16 h16;
typedef _Float16 f16x8 __attribute__((ext_vector_type(8)));
typedef _Float16 f16x4 __attribute__((ext_vector_type(4)));
typedef _Float16 f16x2 __attribute__((ext_vector_type(2)));
typedef float    f32x4 __attribute__((ext_vector_type(4)));

constexpr int T_SEQ = 512;
constexpr int B_SZ  = 1024;
constexpr int H_DIM = 128;
constexpr int ROWS  = 16;    // batch rows per block (MFMA N-tile)
constexpr int NT    = 512;   // 8 waves

__device__ __forceinline__ float sigm(float x) {
  x = fminf(fmaxf(x, -30.f), 30.f);
  return 1.f / (1.f + __expf(-x));
}
__device__ __forceinline__ float tanh_(float x) {
  x = fminf(fmaxf(x, -15.f), 15.f);
  const float e = __expf(2.f * x);
  return 1.f - 2.f / (e + 1.f);
}

// x [B][T][64] fp32  ->  x16 [T][B][64] fp16
__global__ __launch_bounds__(512)
void x_to_f16(const float* __restrict__ x, h16* __restrict__ x16) {
  const int t = blockIdx.x;
  for (int idx = threadIdx.x; idx < B_SZ * 64; idx += 512) {
    const int b = idx >> 6, i = idx & 63;
    x16[(size_t)t * B_SZ * 64 + idx] = (h16)x[((size_t)b * T_SEQ + t) * 64 + i];
  }
}

// Persistent MFMA GRU layer. Block owns ROWS=16 batch rows for all T steps.
// Wave w owns gate-columns [16w,16w+16): r/z/n weight rows of BOTH w_hh
// (GEMM_A over h) and w_ih (GEMM_B over x) as fp16 A-frags in registers.
// h||x live fp16 in LDS; pre-gates stay entirely in the D-registers:
// D layout (m89): col = lane&15 = batch, row = (lane>>4)*4 + reg = gate,
// so r/z/n for the same (gate j, batch c) land in the SAME lane & reg idx.
template <int INDIM, bool STORE_ALL>
__global__ __launch_bounds__(NT, 1)
void gru_mfma(const h16* __restrict__ in,     // [T][B][INDIM] fp16
              const float* __restrict__ w_ih, // [384][INDIM]
              const float* __restrict__ w_hh, // [384][128]
              const float* __restrict__ b_ih, // [384]
              const float* __restrict__ b_hh, // [384]
              h16*  __restrict__ h1out,       // [T][B][128]   (STORE_ALL)
              float* __restrict__ h2out)      // [B][128]      (!STORE_ALL)
{
  constexpr int KSH  = H_DIM / 32;     // 4 K-steps over h
  constexpr int KSX  = INDIM / 32;     // 2 (l0) or 4 (l1) K-steps over x
  constexpr int KTOT = H_DIM + INDIM;
  constexpr int ROWP = KTOT + 8;       // pad: rows land on distinct banks

  __shared__ __align__(16) h16 hx[ROWS][ROWP];   // [batch][h(128) | x(INDIM) | pad]

  const int tid = threadIdx.x;
  const int wv  = tid >> 6;        // wave 0..7 -> gate-col group
  const int ln  = tid & 63;
  const int q   = ln >> 4;         // k-group / D-row group
  const int lr  = ln & 15;         // A: M-row within tile; B/D: batch col
  const int r0  = blockIdx.x * ROWS;
  const int j0  = wv * 16 + q * 4; // first of this lane's 4 gate cols

  // ---- weights -> fp16 A-frags (registers/AGPRs), once ----
  // part p: 0=r rows, 1=z rows, 2=n rows; gate row = p*128 + wv*16 + lr
  f16x8 wA[3][KSH];
  f16x8 wB[3][KSX];
  #pragma unroll
  for (int p = 0; p < 3; ++p) {
    const int g = p * H_DIM + wv * 16 + lr;
    #pragma unroll
    for (int ks = 0; ks < KSH; ++ks) {
      const float* pw = w_hh + (size_t)g * H_DIM + ks * 32 + q * 8;
      const float4 v0 = *(const float4*)(pw);
      const float4 v1 = *(const float4*)(pw + 4);
      f16x8 f;
      f[0]=(h16)v0.x; f[1]=(h16)v0.y; f[2]=(h16)v0.z; f[3]=(h16)v0.w;
      f[4]=(h16)v1.x; f[5]=(h16)v1.y; f[6]=(h16)v1.z; f[7]=(h16)v1.w;
      wA[p][ks] = f;
    }
    #pragma unroll
    for (int ks = 0; ks < KSX; ++ks) {
      const float* pw = w_ih + (size_t)g * INDIM + ks * 32 + q * 8;
      const float4 v0 = *(const float4*)(pw);
      const float4 v1 = *(const float4*)(pw + 4);
      f16x8 f;
      f[0]=(h16)v0.x; f[1]=(h16)v0.y; f[2]=(h16)v0.z; f[3]=(h16)v0.w;
      f[4]=(h16)v1.x; f[5]=(h16)v1.y; f[6]=(h16)v1.z; f[7]=(h16)v1.w;
      wB[p][ks] = f;
    }
  }

  // per-lane gate biases for its 4 gate cols j0..j0+3
  float crv[4], czv[4], binv[4], bhnv[4];
  #pragma unroll
  for (int e = 0; e < 4; ++e) {
    crv[e]  = b_ih[j0 + e] + b_hh[j0 + e];
    czv[e]  = b_ih[128 + j0 + e] + b_hh[128 + j0 + e];
    binv[e] = b_ih[256 + j0 + e];
    bhnv[e] = b_hh[256 + j0 + e];
  }

  // staging ids for x-half of hx: thread -> (row sr, chunk si)
  const int sr = tid >> 5;         // 0..15
  const int si = tid & 31;         // 0..31

  // ---- prologue: h=0, stage x(0) ----
  for (int idx = tid; idx < ROWS * H_DIM; idx += NT)
    hx[idx >> 7][idx & 127] = (h16)0.f;
  if constexpr (INDIM == 128) {
    const f16x4 s = *(const f16x4*)(in + ((size_t)0 * B_SZ + r0 + sr) * 128 + si * 4);
    *(f16x4*)&hx[sr][128 + si * 4] = s;
  } else {
    const f16x2 s = *(const f16x2*)(in + ((size_t)0 * B_SZ + r0 + sr) * 64 + si * 2);
    *(f16x2*)&hx[sr][128 + si * 2] = s;
  }
  __syncthreads();

  #pragma unroll 1
  for (int t = 0; t < T_SEQ; ++t) {
    // ---- MFMA phase: read B-frags (hx@t), prefetch x(t+1), accumulate ----
    f16x8 bh[KSH], bx[KSX];
    #pragma unroll
    for (int ks = 0; ks < KSH; ++ks)
      bh[ks] = *(const f16x8*)&hx[lr][ks * 32 + q * 8];
    #pragma unroll
    for (int ks = 0; ks < KSX; ++ks)
      bx[ks] = *(const f16x8*)&hx[lr][128 + ks * 32 + q * 8];

    const int tt = (t + 1 < T_SEQ) ? t + 1 : t;
    f16x4 stg4; f16x2 stg2;
    if constexpr (INDIM == 128)
      stg4 = *(const f16x4*)(in + ((size_t)tt * B_SZ + r0 + sr) * 128 + si * 4);
    else
      stg2 = *(const f16x2*)(in + ((size_t)tt * B_SZ + r0 + sr) * 64 + si * 2);

    f32x4 accA[3], accB[3];
    #pragma unroll
    for (int p = 0; p < 3; ++p) { accA[p] = (f32x4)(0.f); accB[p] = (f32x4)(0.f); }
    #pragma unroll
    for (int p = 0; p < 3; ++p) {
      #pragma unroll
      for (int ks = 0; ks < KSH; ++ks)
        accA[p] = __builtin_amdgcn_mfma_f32_16x16x32_f16(wA[p][ks], bh[ks], accA[p], 0, 0, 0);
      #pragma unroll
      for (int ks = 0; ks < KSX; ++ks)
        accB[p] = __builtin_amdgcn_mfma_f32_16x16x32_f16(wB[p][ks], bx[ks], accB[p], 0, 0, 0);
    }

    // ---- gate math fully in-lane: this lane owns (batch c=lr, gates j0..j0+3)
    const f16x4 ho4 = *(const f16x4*)&hx[lr][j0];
    f16x4 nv4;
    float hnv[4];
    #pragma unroll
    for (int i = 0; i < 4; ++i) {
      const float rv = sigm(accA[0][i] + accB[0][i] + crv[i]);
      const float zv = sigm(accA[1][i] + accB[1][i] + czv[i]);
      const float nv = tanh_(accB[2][i] + binv[i] + rv * (accA[2][i] + bhnv[i]));
      const float ho = (float)ho4[i];
      const float hn = nv + zv * (ho - nv);
      hnv[i] = hn;
      nv4[i] = (h16)hn;
    }

    __syncthreads();   // B1: all waves finished reading hx@t

    *(f16x4*)&hx[lr][j0] = nv4;               // h(t+1) into LDS
    if constexpr (STORE_ALL) {
      *(f16x4*)&h1out[((size_t)t * B_SZ + r0 + lr) * H_DIM + j0] = nv4;
    } else {
      if (t == T_SEQ - 1)
        *(float4*)&h2out[(size_t)(r0 + lr) * H_DIM + j0] =
            make_float4(hnv[0], hnv[1], hnv[2], hnv[3]);
    }
    if constexpr (INDIM == 128) *(f16x4*)&hx[sr][128 + si * 4] = stg4;
    else                        *(f16x2*)&hx[sr][128 + si * 2] = stg2;

    __syncthreads();   // B2: hx@t+1 ready
  }
}

// FC head: out = fc2( BN( relu( fc1(h2_last) ) ) ); one row per block.
__global__ __launch_bounds__(64)
void head_kernel(const float* __restrict__ h2,     // (B, H) f32
                 const float* __restrict__ fc1_w,  // (64, 128)
                 const float* __restrict__ fc1_b,  // (64)
                 const float* __restrict__ fc2_w,  // (2, 64)
                 const float* __restrict__ fc2_b,  // (2)
                 const float* __restrict__ gamma,
                 const float* __restrict__ beta,
                 const float* __restrict__ mean,
                 const float* __restrict__ var,
                 float* __restrict__ out)          // (B, 2)
{
  const int row = blockIdx.x;
  const int j   = threadIdx.x;   // 0..63
  __shared__ __align__(16) float hrow[H_DIM];
  __shared__ __align__(16) float act[64];

  hrow[j]      = h2[(size_t)row * H_DIM + j];
  hrow[64 + j] = h2[(size_t)row * H_DIM + 64 + j];
  __syncthreads();

  float s = fc1_b[j];
  const float4* wr = reinterpret_cast<const float4*>(fc1_w + (size_t)j * H_DIM);
  #pragma unroll
  for (int k4 = 0; k4 < H_DIM / 4; ++k4) {
    const float4 w = wr[k4];
    const float4 h = reinterpret_cast<const float4*>(hrow)[k4];
    s += w.x * h.x + w.y * h.y + w.z * h.z + w.w * h.w;
  }
  s = fmaxf(s, 0.f);
  s = (s - mean[j]) * rsqrtf(var[j] + 1e-5f) * gamma[j] + beta[j];
  act[j] = s;
  __syncthreads();

  if (j < 2) {
    float o = fc2_b[j];
    #pragma unroll
    for (int k = 0; k < 64; ++k) o += fc2_w[(size_t)j * 64 + k] * act[k];
    out[(size_t)row * 2 + j] = o;
  }
}

} // namespace

extern "C" void kernel_launch(void* const* d_in, const int* in_sizes, int n_in,
                              void* d_out, int out_size, void* d_ws, size_t ws_size,
                              hipStream_t stream) {
  const float* x     = (const float*)d_in[0];
  const float* w_ih0 = (const float*)d_in[1];
  const float* w_hh0 = (const float*)d_in[2];
  const float* b_ih0 = (const float*)d_in[3];
  const float* b_hh0 = (const float*)d_in[4];
  const float* w_ih1 = (const float*)d_in[5];
  const float* w_hh1 = (const float*)d_in[6];
  const float* b_ih1 = (const float*)d_in[7];
  const float* b_hh1 = (const float*)d_in[8];
  const float* fc1_w = (const float*)d_in[9];
  const float* fc1_b = (const float*)d_in[10];
  const float* fc2_w = (const float*)d_in[11];
  const float* fc2_b = (const float*)d_in[12];
  const float* gamma = (const float*)d_in[13];
  const float* beta  = (const float*)d_in[14];
  const float* mean  = (const float*)d_in[15];
  const float* var   = (const float*)d_in[16];
  float* out = (float*)d_out;

  char* ws = (char*)d_ws;
  const size_t h2_bytes  = (size_t)B_SZ * H_DIM * sizeof(float);          // 512 KB
  const size_t x16_bytes = (size_t)T_SEQ * B_SZ * 64 * sizeof(h16);      // 67 MB
  const size_t h1_bytes  = (size_t)T_SEQ * B_SZ * H_DIM * sizeof(h16);   // 134 MB
  if (ws_size < h2_bytes + x16_bytes + h1_bytes) return;  // fail visibly

  float* h2  = (float*)ws;
  h16*   x16 = (h16*)(ws + h2_bytes);
  h16*   h1  = (h16*)(ws + h2_bytes + x16_bytes);

  x_to_f16<<<dim3(T_SEQ), dim3(512), 0, stream>>>(x, x16);
  gru_mfma<64, true><<<dim3(B_SZ / ROWS), dim3(NT), 0, stream>>>(
      x16, w_ih0, w_hh0, b_ih0, b_hh0, h1, nullptr);
  gru_mfma<128, false><<<dim3(B_SZ / ROWS), dim3(NT), 0, stream>>>(
      h1, w_ih1, w_hh1, b_ih1, b_hh1, nullptr, h2);
  head_kernel<<<dim3(B_SZ), dim3(64), 0, stream>>>(
      h2, fc1_w, fc1_b, fc2_w, fc2_b, gamma, beta, mean, var, out);
}

// Round 5
// 748.060 us; speedup vs baseline: 15.5755x; 1.7445x over previous
//
#include <hip/hip_runtime.h>
#include <hip/hip_bf16.h>

namespace {

typedef _Float16 h16;
typedef _Float16 f16x8 __attribute__((ext_vector_type(8)));
typedef _Float16 f16x4 __attribute__((ext_vector_type(4)));
typedef _Float16 f16x2 __attribute__((ext_vector_type(2)));
typedef float    f32x4 __attribute__((ext_vector_type(4)));

constexpr int T_SEQ = 512;
constexpr int B_SZ  = 1024;
constexpr int H_DIM = 128;
constexpr int ROWS  = 16;    // batch rows per block (MFMA N-tile)
constexpr int NT    = 512;   // 8 waves

// Persistent MFMA GRU layer, latency-tuned:
//  - hx double-buffered -> ONE barrier per step
//  - h_old kept in registers (the producing lane is the consuming lane)
//  - input prefetch 2 steps deep (statically named regs, no runtime indexing)
//  - biases folded into MFMA C-init
//  - activations without clamps (exp saturates to correct limits)
// Verified frag convention (round 4, absmax 1.2e-4):
//  A row = lane&15 (gate-within-16), k = (lane>>4)*8 + e + 32*ks
//  B col = lane&15 (batch), same k;  D: col=lane&15, row=(lane>>4)*4+i
template <int INDIM, typename InT, bool STORE_ALL>
__global__ __launch_bounds__(NT, 1)
void gru_mfma(const InT* __restrict__ in,     // l0: x [B][T][64] f32; l1: h1 [T][B][128] f16
              const float* __restrict__ w_ih, // [384][INDIM]
              const float* __restrict__ w_hh, // [384][128]
              const float* __restrict__ b_ih, // [384]
              const float* __restrict__ b_hh, // [384]
              h16*  __restrict__ h1out,       // [T][B][128]   (STORE_ALL)
              float* __restrict__ h2out)      // [B][128]      (!STORE_ALL)
{
  constexpr int KSH  = H_DIM / 32;     // 4 K-steps over h
  constexpr int KSX  = INDIM / 32;     // 2 (l0) or 4 (l1) K-steps over input
  constexpr int KTOT = H_DIM + INDIM;
  constexpr int ROWP = KTOT + 8;       // +16B pad: row stride ≡ 4 mod 32 dwords (2-way = free)

  __shared__ __align__(16) h16 hx[2][ROWS][ROWP];  // [buf][batch][h(128) | in(INDIM) | pad]

  const int tid = threadIdx.x;
  const int wv  = tid >> 6;        // wave 0..7 -> gate-col group
  const int ln  = tid & 63;
  const int q   = ln >> 4;         // k-chunk / D-row group
  const int lr  = ln & 15;         // A: gate row within 16; B/D: batch col
  const int r0  = blockIdx.x * ROWS;
  const int j0  = wv * 16 + q * 4; // first of this lane's 4 gate cols

  // ---- weights -> fp16 frags (registers/AGPRs), once ----
  f16x8 wA[3][KSH];   // w_hh rows (recurrent GEMM A-operand)
  f16x8 wB[3][KSX];   // w_ih rows (input GEMM A-operand)
  #pragma unroll
  for (int p = 0; p < 3; ++p) {
    const int g = p * H_DIM + wv * 16 + lr;
    #pragma unroll
    for (int ks = 0; ks < KSH; ++ks) {
      const float* pw = w_hh + (size_t)g * H_DIM + ks * 32 + q * 8;
      const float4 v0 = *(const float4*)(pw);
      const float4 v1 = *(const float4*)(pw + 4);
      f16x8 f;
      f[0]=(h16)v0.x; f[1]=(h16)v0.y; f[2]=(h16)v0.z; f[3]=(h16)v0.w;
      f[4]=(h16)v1.x; f[5]=(h16)v1.y; f[6]=(h16)v1.z; f[7]=(h16)v1.w;
      wA[p][ks] = f;
    }
    #pragma unroll
    for (int ks = 0; ks < KSX; ++ks) {
      const float* pw = w_ih + (size_t)g * INDIM + ks * 32 + q * 8;
      const float4 v0 = *(const float4*)(pw);
      const float4 v1 = *(const float4*)(pw + 4);
      f16x8 f;
      f[0]=(h16)v0.x; f[1]=(h16)v0.y; f[2]=(h16)v0.z; f[3]=(h16)v0.w;
      f[4]=(h16)v1.x; f[5]=(h16)v1.y; f[6]=(h16)v1.z; f[7]=(h16)v1.w;
      wB[p][ks] = f;
    }
  }

  // ---- bias C-init vectors for this lane's 4 gate cols ----
  f32x4 bR, bZ, bNx, bNh;
  {
    const float4 ir = *(const float4*)&b_ih[j0];
    const float4 hr = *(const float4*)&b_hh[j0];
    const float4 iz = *(const float4*)&b_ih[H_DIM + j0];
    const float4 hz = *(const float4*)&b_hh[H_DIM + j0];
    const float4 in_ = *(const float4*)&b_ih[2 * H_DIM + j0];
    const float4 hn = *(const float4*)&b_hh[2 * H_DIM + j0];
    bR[0]=ir.x+hr.x; bR[1]=ir.y+hr.y; bR[2]=ir.z+hr.z; bR[3]=ir.w+hr.w;
    bZ[0]=iz.x+hz.x; bZ[1]=iz.y+hz.y; bZ[2]=iz.z+hz.z; bZ[3]=iz.w+hz.w;
    bNx[0]=in_.x; bNx[1]=in_.y; bNx[2]=in_.z; bNx[3]=in_.w;
    bNh[0]=hn.x;  bNh[1]=hn.y;  bNh[2]=hn.z;  bNh[3]=hn.w;
  }

  // ---- staging ids: thread -> (batch row sr, chunk si) ----
  const int sr = tid >> 5;         // 0..15
  const int si = tid & 31;         // 0..31

  auto load_stage = [&](int t, f16x4& dst) {
    if constexpr (INDIM == 64) {   // x is [B][T][64] f32 -> convert inline
      const float2 v = *(const float2*)(in + ((size_t)(r0 + sr) * T_SEQ + t) * 64 + si * 2);
      dst[0] = (h16)v.x; dst[1] = (h16)v.y;
    } else {                       // h1 is [T][B][128] f16
      dst = *(const f16x4*)(in + ((size_t)t * B_SZ + (r0 + sr)) * 128 + si * 4);
    }
  };
  auto write_stage = [&](int buf, const f16x4& s) {
    if constexpr (INDIM == 64) {
      f16x2 v; v[0] = s[0]; v[1] = s[1];
      *(f16x2*)&hx[buf][sr][H_DIM + si * 2] = v;
    } else {
      *(f16x4*)&hx[buf][sr][H_DIM + si * 4] = s;
    }
  };

  // ---- prologue: h(0)=0 and in(0) into buf 0; in(1) into regs ----
  {
    const int zr = tid >> 5, zc = (tid & 31) * 4;   // 16 x 128 h16 = 512 x f16x4
    f16x4 z; z[0] = z[1] = z[2] = z[3] = (h16)0.f;
    *(f16x4*)&hx[0][zr][zc] = z;
  }
  f16x4 s0; load_stage(0, s0); write_stage(0, s0);
  f16x4 sA; load_stage(1, sA);    // in(1), written during step 0
  f16x4 sB;                       // in(2), loaded during step 0
  f16x4 h_old; h_old[0] = h_old[1] = h_old[2] = h_old[3] = (h16)0.f;
  __syncthreads();

  auto step = [&](int t, int cur, f16x4& s_use, f16x4& s_load) {
    // B-frags from hx[cur]
    f16x8 bh[KSH], bx[KSX];
    #pragma unroll
    for (int ks = 0; ks < KSH; ++ks)
      bh[ks] = *(const f16x8*)&hx[cur][lr][ks * 32 + q * 8];
    #pragma unroll
    for (int ks = 0; ks < KSX; ++ks)
      bx[ks] = *(const f16x8*)&hx[cur][lr][H_DIM + ks * 32 + q * 8];

    // prefetch in(t+2) — 2-step window hides HBM latency
    load_stage((t + 2 < T_SEQ) ? t + 2 : T_SEQ - 1, s_load);

    // MFMA: 4 independent chains, biases pre-loaded as C-init
    f32x4 aR = bR, aZ = bZ, aNh = bNh, aNx = bNx;
    #pragma unroll
    for (int ks = 0; ks < KSH; ++ks) {
      aR  = __builtin_amdgcn_mfma_f32_16x16x32_f16(wA[0][ks], bh[ks], aR, 0, 0, 0);
      aZ  = __builtin_amdgcn_mfma_f32_16x16x32_f16(wA[1][ks], bh[ks], aZ, 0, 0, 0);
      aNh = __builtin_amdgcn_mfma_f32_16x16x32_f16(wA[2][ks], bh[ks], aNh, 0, 0, 0);
    }
    #pragma unroll
    for (int ks = 0; ks < KSX; ++ks) {
      aR  = __builtin_amdgcn_mfma_f32_16x16x32_f16(wB[0][ks], bx[ks], aR, 0, 0, 0);
      aZ  = __builtin_amdgcn_mfma_f32_16x16x32_f16(wB[1][ks], bx[ks], aZ, 0, 0, 0);
      aNx = __builtin_amdgcn_mfma_f32_16x16x32_f16(wB[2][ks], bx[ks], aNx, 0, 0, 0);
    }

    // gates, fully in-lane; h_old is this lane's own previous output
    f16x4 nv4;
    float hnv[4];
    #pragma unroll
    for (int i = 0; i < 4; ++i) {
      const float rg = __builtin_amdgcn_rcpf(1.f + __expf(-aR[i]));
      const float zg = __builtin_amdgcn_rcpf(1.f + __expf(-aZ[i]));
      const float na = aNx[i] + rg * aNh[i];
      const float e2 = __expf(2.f * na);
      const float ng = 1.f - 2.f * __builtin_amdgcn_rcpf(e2 + 1.f);
      const float ho = (float)h_old[i];
      const float hn = ng + zg * (ho - ng);
      hnv[i] = hn;
      nv4[i] = (h16)hn;
    }
    h_old = nv4;

    // writes go to the OTHER buffer — no race with this step's readers
    *(f16x4*)&hx[cur ^ 1][lr][j0] = nv4;
    write_stage(cur ^ 1, s_use);
    if constexpr (STORE_ALL) {
      *(f16x4*)&h1out[((size_t)t * B_SZ + r0 + lr) * H_DIM + j0] = nv4;
    } else {
      if (t == T_SEQ - 1)
        *(float4*)&h2out[(size_t)(r0 + lr) * H_DIM + j0] =
            make_float4(hnv[0], hnv[1], hnv[2], hnv[3]);
    }
    __syncthreads();   // the single barrier: buf[cur^1] complete
  };

  #pragma unroll 1
  for (int t = 0; t < T_SEQ; t += 2) {
    step(t,     0, sA, sB);   // reads buf0, writes buf1; stages in(t+1), loads in(t+2)
    step(t + 1, 1, sB, sA);   // reads buf1, writes buf0; stages in(t+2), loads in(t+3)
  }
}

// FC head: out = fc2( BN( relu( fc1(h2_last) ) ) ); one row per block.
__global__ __launch_bounds__(64)
void head_kernel(const float* __restrict__ h2,     // (B, H) f32
                 const float* __restrict__ fc1_w,  // (64, 128)
                 const float* __restrict__ fc1_b,  // (64)
                 const float* __restrict__ fc2_w,  // (2, 64)
                 const float* __restrict__ fc2_b,  // (2)
                 const float* __restrict__ gamma,
                 const float* __restrict__ beta,
                 const float* __restrict__ mean,
                 const float* __restrict__ var,
                 float* __restrict__ out)          // (B, 2)
{
  const int row = blockIdx.x;
  const int j   = threadIdx.x;   // 0..63
  __shared__ __align__(16) float hrow[H_DIM];
  __shared__ __align__(16) float act[64];

  hrow[j]      = h2[(size_t)row * H_DIM + j];
  hrow[64 + j] = h2[(size_t)row * H_DIM + 64 + j];
  __syncthreads();

  float s = fc1_b[j];
  const float4* wr = reinterpret_cast<const float4*>(fc1_w + (size_t)j * H_DIM);
  #pragma unroll
  for (int k4 = 0; k4 < H_DIM / 4; ++k4) {
    const float4 w = wr[k4];
    const float4 h = reinterpret_cast<const float4*>(hrow)[k4];
    s += w.x * h.x + w.y * h.y + w.z * h.z + w.w * h.w;
  }
  s = fmaxf(s, 0.f);
  s = (s - mean[j]) * rsqrtf(var[j] + 1e-5f) * gamma[j] + beta[j];
  act[j] = s;
  __syncthreads();

  if (j < 2) {
    float o = fc2_b[j];
    #pragma unroll
    for (int k = 0; k < 64; ++k) o += fc2_w[(size_t)j * 64 + k] * act[k];
    out[(size_t)row * 2 + j] = o;
  }
}

} // namespace

extern "C" void kernel_launch(void* const* d_in, const int* in_sizes, int n_in,
                              void* d_out, int out_size, void* d_ws, size_t ws_size,
                              hipStream_t stream) {
  const float* x     = (const float*)d_in[0];
  const float* w_ih0 = (const float*)d_in[1];
  const float* w_hh0 = (const float*)d_in[2];
  const float* b_ih0 = (const float*)d_in[3];
  const float* b_hh0 = (const float*)d_in[4];
  const float* w_ih1 = (const float*)d_in[5];
  const float* w_hh1 = (const float*)d_in[6];
  const float* b_ih1 = (const float*)d_in[7];
  const float* b_hh1 = (const float*)d_in[8];
  const float* fc1_w = (const float*)d_in[9];
  const float* fc1_b = (const float*)d_in[10];
  const float* fc2_w = (const float*)d_in[11];
  const float* fc2_b = (const float*)d_in[12];
  const float* gamma = (const float*)d_in[13];
  const float* beta  = (const float*)d_in[14];
  const float* mean  = (const float*)d_in[15];
  const float* var   = (const float*)d_in[16];
  float* out = (float*)d_out;

  char* ws = (char*)d_ws;
  const size_t h2_bytes = (size_t)B_SZ * H_DIM * sizeof(float);           // 512 KB
  const size_t h1_bytes = (size_t)T_SEQ * B_SZ * H_DIM * sizeof(h16);     // 134 MB
  if (ws_size < h2_bytes + h1_bytes) return;  // fail visibly

  float* h2 = (float*)ws;
  h16*   h1 = (h16*)(ws + h2_bytes);

  gru_mfma<64, float, true><<<dim3(B_SZ / ROWS), dim3(NT), 0, stream>>>(
      x, w_ih0, w_hh0, b_ih0, b_hh0, h1, nullptr);
  gru_mfma<128, h16, false><<<dim3(B_SZ / ROWS), dim3(NT), 0, stream>>>(
      h1, w_ih1, w_hh1, b_ih1, b_hh1, nullptr, h2);
  head_kernel<<<dim3(B_SZ), dim3(64), 0, stream>>>(
      h2, fc1_w, fc1_b, fc2_w, fc2_b, gamma, beta, mean, var, out);
}